// Round 5
// baseline (43.168 us; speedup 1.0000x reference)
//
#include <hip/hip_runtime.h>

#define BB 4
#define SS 4096
#define HH 2048
#define KK 2048   // int(0.5 * 4096)

typedef float f4 __attribute__((ext_vector_type(4)));   // native vec for nontemporal builtin

// ---- scores: one wave per 4 consecutive rows, gate cached in registers ----
// (identical to R4 — structure-insensitive per R2 vs R4, near read-BW floor)

__device__ __forceinline__ void load_row(const f4* __restrict__ base, int lane,
                                         f4 (&buf)[8]) {
#pragma unroll
    for (int i = 0; i < 8; ++i)
        buf[i] = __builtin_nontemporal_load(&base[i * 64 + lane]);
}

__device__ __forceinline__ double dot_row(const f4 (&a)[8], const f4 (&g)[8]) {
    double ax = 0.0, ay = 0.0, az = 0.0, aw = 0.0;
#pragma unroll
    for (int i = 0; i < 8; ++i) {
        ax = fma((double)a[i].x, (double)g[i].x, ax);
        ay = fma((double)a[i].y, (double)g[i].y, ay);
        az = fma((double)a[i].z, (double)g[i].z, az);
        aw = fma((double)a[i].w, (double)g[i].w, aw);
    }
    return (ax + ay) + (az + aw);
}

__device__ __forceinline__ void reduce_store(double acc, int lane, float* __restrict__ dst) {
#pragma unroll
    for (int off = 32; off >= 1; off >>= 1)
        acc += __shfl_down(acc, off);
    if (lane == 0) *dst = (float)acc;
}

__global__ void __launch_bounds__(256)
scores_kernel(const float* __restrict__ hs,
              const float* __restrict__ gw,
              float* __restrict__ scores) {
    int wave = threadIdx.x >> 6;
    int lane = threadIdx.x & 63;
    int row0 = blockIdx.x * 16 + wave * 4;

    const f4* g4 = reinterpret_cast<const f4*>(gw);
    f4 g[8];
#pragma unroll
    for (int i = 0; i < 8; ++i) g[i] = g4[i * 64 + lane];

    const f4* r0 = reinterpret_cast<const f4*>(hs + (size_t)row0 * HH);
    f4 A[8], B[8];
    load_row(r0 + 0 * 512, lane, A);
    load_row(r0 + 1 * 512, lane, B);
    double d0 = dot_row(A, g);
    load_row(r0 + 2 * 512, lane, A);
    double d1 = dot_row(B, g);
    load_row(r0 + 3 * 512, lane, B);
    double d2 = dot_row(A, g);
    double d3 = dot_row(B, g);

    reduce_store(d0, lane, scores + row0 + 0);
    reduce_store(d1, lane, scores + row0 + 1);
    reduce_store(d2, lane, scores + row0 + 2);
    reduce_store(d3, lane, scores + row0 + 3);
}

// ---- topk: one wave per batch; ALL cross-lane counts via ballot+popcount ----
// Per round: 64 x { v_cmp (VALU) + s_bcnt1_b64/s_add (scalar pipe) } — no
// shuffles, no VCC-serialized accumulate, count lands wave-uniform in SGPR.
__global__ void __launch_bounds__(64)
topk_mask_kernel(const float* __restrict__ scores, float* __restrict__ mask) {
    int b    = blockIdx.x;
    int lane = threadIdx.x;
    const float* sc = scores + b * SS;

    unsigned ord[64];
#pragma unroll
    for (int i = 0; i < 64; ++i) {
        unsigned u = __float_as_uint(sc[i * 64 + lane]);
        ord[i] = (u & 0x80000000u) ? ~u : (u | 0x80000000u);
    }

    // MSB-first binary search for the largest T with count(ord >= T) >= K.
    // Early exit when count == K (candidate lands in the (v_{K+1}, v_K] gap,
    // ~2^19 ULP wide for N(0,45) scores => ~13 rounds typical).
    unsigned cur = 0u;
    for (int bit = 31; bit >= 0; --bit) {
        unsigned cand = cur | (1u << bit);
        int c = 0;
#pragma unroll
        for (int i = 0; i < 64; ++i)
            c += (int)__popcll(__ballot(ord[i] >= cand));
        if (c >= KK) cur = cand;
        if (c == KK) break;
    }

    // strictly-greater count -> number of ties to admit (lowest index first)
    int cg = 0;
#pragma unroll
    for (int i = 0; i < 64; ++i)
        cg += (int)__popcll(__ballot(ord[i] > cur));
    int r = KK - cg;

    unsigned long long lane_lt = (lane == 0) ? 0ull : (~0ull >> (64 - lane));
    int tiepfx = 0;
    float* mrow = mask + b * SS;
#pragma unroll
    for (int i = 0; i < 64; ++i) {
        bool gt  = ord[i] > cur;
        bool tie = ord[i] == cur;
        unsigned long long bal = __ballot(tie);
        int rank = tiepfx + (int)__popcll(bal & lane_lt);
        mrow[i * 64 + lane] = (gt || (tie && rank < r)) ? 1.0f : 0.0f;
        tiepfx += (int)__popcll(bal);
    }
}

extern "C" void kernel_launch(void* const* d_in, const int* in_sizes, int n_in,
                              void* d_out, int out_size, void* d_ws, size_t ws_size,
                              hipStream_t stream) {
    const float* hs = (const float*)d_in[0];   // [B, S, H] fp32
    const float* gw = (const float*)d_in[1];   // [1, H] fp32
    float* out    = (float*)d_out;
    float* mask   = out;            // first output chunk  [B*S]
    float* scores = out + BB * SS;  // second output chunk [B*S]

    scores_kernel<<<BB * SS / 16, 256, 0, stream>>>(hs, gw, scores);
    topk_mask_kernel<<<BB, 64, 0, stream>>>(scores, mask);
}

// Round 6
// 31.291 us; speedup vs baseline: 1.3796x; 1.3796x over previous
//
#include <hip/hip_runtime.h>

#define BB 4
#define SS 4096
#define HH 2048
#define KK 2048   // int(0.5 * 4096)

typedef float f4 __attribute__((ext_vector_type(4)));   // native vec for nontemporal builtin

// ---- scores: one wave per 4 consecutive rows, gate cached in registers ----
// (byte-identical to R4 — proven, ~read-BW floor)

__device__ __forceinline__ void load_row(const f4* __restrict__ base, int lane,
                                         f4 (&buf)[8]) {
#pragma unroll
    for (int i = 0; i < 8; ++i)
        buf[i] = __builtin_nontemporal_load(&base[i * 64 + lane]);
}

__device__ __forceinline__ double dot_row(const f4 (&a)[8], const f4 (&g)[8]) {
    double ax = 0.0, ay = 0.0, az = 0.0, aw = 0.0;
#pragma unroll
    for (int i = 0; i < 8; ++i) {
        ax = fma((double)a[i].x, (double)g[i].x, ax);
        ay = fma((double)a[i].y, (double)g[i].y, ay);
        az = fma((double)a[i].z, (double)g[i].z, az);
        aw = fma((double)a[i].w, (double)g[i].w, aw);
    }
    return (ax + ay) + (az + aw);
}

__device__ __forceinline__ void reduce_store(double acc, int lane, float* __restrict__ dst) {
#pragma unroll
    for (int off = 32; off >= 1; off >>= 1)
        acc += __shfl_down(acc, off);
    if (lane == 0) *dst = (float)acc;
}

__global__ void __launch_bounds__(256)
scores_kernel(const float* __restrict__ hs,
              const float* __restrict__ gw,
              float* __restrict__ scores) {
    int wave = threadIdx.x >> 6;
    int lane = threadIdx.x & 63;
    int row0 = blockIdx.x * 16 + wave * 4;

    const f4* g4 = reinterpret_cast<const f4*>(gw);
    f4 g[8];
#pragma unroll
    for (int i = 0; i < 8; ++i) g[i] = g4[i * 64 + lane];

    const f4* r0 = reinterpret_cast<const f4*>(hs + (size_t)row0 * HH);
    f4 A[8], B[8];
    load_row(r0 + 0 * 512, lane, A);
    load_row(r0 + 1 * 512, lane, B);
    double d0 = dot_row(A, g);
    load_row(r0 + 2 * 512, lane, A);
    double d1 = dot_row(B, g);
    load_row(r0 + 3 * 512, lane, B);
    double d2 = dot_row(A, g);
    double d3 = dot_row(B, g);

    reduce_store(d0, lane, scores + row0 + 0);
    reduce_store(d1, lane, scores + row0 + 1);
    reduce_store(d2, lane, scores + row0 + 2);
    reduce_store(d3, lane, scores + row0 + 3);
}

// ---- topk: 4 waves per batch, DPP reduce, exact-exit fast path ----

__device__ __forceinline__ unsigned to_ord(float f) {
    unsigned u = __float_as_uint(f);
    return (u & 0x80000000u) ? ~u : (u | 0x80000000u);
}

// full-wave (64-lane) sum; returns wave-uniform total via readlane(63)
__device__ __forceinline__ int dpp_wave_sum(int v) {
    v += __builtin_amdgcn_update_dpp(0, v, 0x111, 0xF, 0xF, true);  // row_shr:1
    v += __builtin_amdgcn_update_dpp(0, v, 0x112, 0xF, 0xF, true);  // row_shr:2
    v += __builtin_amdgcn_update_dpp(0, v, 0x114, 0xF, 0xF, true);  // row_shr:4
    v += __builtin_amdgcn_update_dpp(0, v, 0x118, 0xF, 0xF, true);  // row_shr:8
    v += __builtin_amdgcn_update_dpp(0, v, 0x142, 0xF, 0xF, true);  // row_bcast:15
    v += __builtin_amdgcn_update_dpp(0, v, 0x143, 0xF, 0xF, true);  // row_bcast:31
    return __builtin_amdgcn_readlane(v, 63);
}

__global__ void __launch_bounds__(256)
topk_mask_kernel(const float* __restrict__ scores, float* __restrict__ mask) {
    int b = blockIdx.x, t = threadIdx.x;
    int w = t >> 6, lane = t & 63;
    const f4* sc4 = reinterpret_cast<const f4*>(scores + b * SS);

    // thread t owns 16 consecutive scores [t*16, t*16+16) -> dwordx4 loads
    f4 v[4];
#pragma unroll
    for (int i = 0; i < 4; ++i) v[i] = sc4[t * 4 + i];

    unsigned ord[16];
#pragma unroll
    for (int i = 0; i < 4; ++i) {
        ord[4 * i + 0] = to_ord(v[i].x);
        ord[4 * i + 1] = to_ord(v[i].y);
        ord[4 * i + 2] = to_ord(v[i].z);
        ord[4 * i + 3] = to_ord(v[i].w);
    }

    __shared__ int wsum[2][4];
    __shared__ int tts[256];

    // MSB-first binary search for largest T with count(ord >= T) >= K.
    // Early exit when count == K: plane is exact, mask = (ord >= T).
    unsigned cur = 0u, thresh = 0u;
    bool exact = false;
    int par = 0;
    for (int bit = 31; bit >= 0; --bit) {
        unsigned cand = cur | (1u << bit);
        int c = 0;
#pragma unroll
        for (int i = 0; i < 16; ++i) c += (ord[i] >= cand) ? 1 : 0;
        int ws = dpp_wave_sum(c);
        if (lane == 0) wsum[par][w] = ws;
        __syncthreads();
        int total = wsum[par][0] + wsum[par][1] + wsum[par][2] + wsum[par][3];
        par ^= 1;
        if (total >= KK) cur = cand;
        if (total == KK) { exact = true; thresh = cand; break; }
    }

    f4* m4 = reinterpret_cast<f4*>(mask + b * SS);

    if (exact) {
#pragma unroll
        for (int i = 0; i < 4; ++i) {
            f4 m;
            m.x = (ord[4 * i + 0] >= thresh) ? 1.0f : 0.0f;
            m.y = (ord[4 * i + 1] >= thresh) ? 1.0f : 0.0f;
            m.z = (ord[4 * i + 2] >= thresh) ? 1.0f : 0.0f;
            m.w = (ord[4 * i + 3] >= thresh) ? 1.0f : 0.0f;
            m4[t * 4 + i] = m;
        }
        return;
    }

    // ---- cold fallback: duplicates straddle the K boundary ----
    // cur == exact K-th largest key value; admit r = K - count(>cur) ties,
    // lowest global index first (thread order == index order here).
    int cgl = 0, ttl = 0;
#pragma unroll
    for (int i = 0; i < 16; ++i) {
        cgl += (ord[i] > cur) ? 1 : 0;
        ttl += (ord[i] == cur) ? 1 : 0;
    }
    int cgw = dpp_wave_sum(cgl);
    if (lane == 0) wsum[0][w] = cgw;
    tts[t] = ttl;
    __syncthreads();
    int cg = wsum[0][0] + wsum[0][1] + wsum[0][2] + wsum[0][3];
    int r = KK - cg;
    if (t == 0) {
        int acc = 0;
        for (int i = 0; i < 256; ++i) { int x = tts[i]; tts[i] = acc; acc += x; }
    }
    __syncthreads();
    int pfx = tts[t];
#pragma unroll
    for (int i = 0; i < 4; ++i) {
        float mm[4];
#pragma unroll
        for (int j = 0; j < 4; ++j) {
            unsigned o = ord[4 * i + j];
            bool gt  = o > cur;
            bool tie = o == cur;
            mm[j] = (gt || (tie && pfx < r)) ? 1.0f : 0.0f;
            if (tie) ++pfx;
        }
        f4 m; m.x = mm[0]; m.y = mm[1]; m.z = mm[2]; m.w = mm[3];
        m4[t * 4 + i] = m;
    }
}

extern "C" void kernel_launch(void* const* d_in, const int* in_sizes, int n_in,
                              void* d_out, int out_size, void* d_ws, size_t ws_size,
                              hipStream_t stream) {
    const float* hs = (const float*)d_in[0];   // [B, S, H] fp32
    const float* gw = (const float*)d_in[1];   // [1, H] fp32
    float* out    = (float*)d_out;
    float* mask   = out;            // first output chunk  [B*S]
    float* scores = out + BB * SS;  // second output chunk [B*S]

    scores_kernel<<<BB * SS / 16, 256, 0, stream>>>(hs, gw, scores);
    topk_mask_kernel<<<BB, 256, 0, stream>>>(scores, mask);
}